// Round 1
// baseline (1521.932 us; speedup 1.0000x reference)
//
#include <hip/hip_runtime.h>

// GCN: 4 layers (64->64->64->64->16), N=100k nodes, E=1.6M edges (+ self loops).
// out[dst] = dis[dst] * ( sum_{edges src->dst} t'[src] + t'[dst] ) + b, t' = dis * (h @ W)

__global__ void k_init_deg(float* __restrict__ deg, int n) {
    int i = blockIdx.x * blockDim.x + threadIdx.x;
    if (i < n) deg[i] = 1.0f;   // self-loop contributes 1
}

__global__ void k_count_deg(const int* __restrict__ dst, int e, float* __restrict__ deg) {
    int stride = gridDim.x * blockDim.x;
    for (int i = blockIdx.x * blockDim.x + threadIdx.x; i < e; i += stride)
        atomicAdd(&deg[dst[i]], 1.0f);
}

__global__ void k_rsqrt(float* __restrict__ d, int n) {
    int i = blockIdx.x * blockDim.x + threadIdx.x;
    if (i < n) d[i] = rsqrtf(d[i]);   // deg >= 1 always (self-loops)
}

// t[i][f] = dis[i] * sum_k x[i][k] * W[k][f]   (FIN = FOUT = 64)
// One wave per row: lane = output feature. x row loaded coalesced, broadcast via readlane/shfl.
__global__ void k_matmul64(const float* __restrict__ x, const float* __restrict__ W,
                           const float* __restrict__ dis, float* __restrict__ t, int n) {
    __shared__ float Ws[64 * 64];
    for (int i = threadIdx.x; i < 64 * 64; i += blockDim.x) Ws[i] = W[i];
    __syncthreads();
    int lane = threadIdx.x & 63;
    int wid  = (blockIdx.x * blockDim.x + threadIdx.x) >> 6;
    int nw   = (gridDim.x * blockDim.x) >> 6;
    for (int row = wid; row < n; row += nw) {
        float xv  = x[(size_t)row * 64 + lane];
        float acc = 0.f;
#pragma unroll
        for (int k = 0; k < 64; ++k) {
            float xk = __shfl(xv, k);          // wave-uniform -> readlane, SGPR operand
            acc = fmaf(xk, Ws[k * 64 + lane], acc);
        }
        t[(size_t)row * 64 + lane] = acc * dis[row];
    }
}

// t[i][f] = dis[i] * sum_k x[i][k] * W[k][f]   (FIN = 64, FOUT = 16)
__global__ void k_matmul16(const float* __restrict__ x, const float* __restrict__ W,
                           const float* __restrict__ dis, float* __restrict__ t, int n) {
    __shared__ float Ws[64 * 16];
    for (int i = threadIdx.x; i < 64 * 16; i += blockDim.x) Ws[i] = W[i];
    __syncthreads();
    int stride = gridDim.x * blockDim.x;
    for (int idx = blockIdx.x * blockDim.x + threadIdx.x; idx < n * 16; idx += stride) {
        int row = idx >> 4, f = idx & 15;
        const float* xr = x + (size_t)row * 64;
        float acc = 0.f;
#pragma unroll
        for (int k = 0; k < 64; ++k) acc = fmaf(xr[k], Ws[k * 16 + f], acc);
        t[idx] = acc * dis[row];
    }
}

// agg[dst][f] += t[src][f], one wave per edge (lane = feature), 256B coalesced
__global__ void k_scatter64(const int* __restrict__ src, const int* __restrict__ dst,
                            const float* __restrict__ t, float* __restrict__ agg, int e) {
    int lane = threadIdx.x & 63;
    int wid  = (blockIdx.x * blockDim.x + threadIdx.x) >> 6;
    int nw   = (gridDim.x * blockDim.x) >> 6;
    for (int i = wid; i < e; i += nw) {
        int s = src[i], d = dst[i];
        atomicAdd(&agg[(size_t)d * 64 + lane], t[(size_t)s * 64 + lane]);
    }
}

// 16-wide scatter: 4 edges per wave
__global__ void k_scatter16(const int* __restrict__ src, const int* __restrict__ dst,
                            const float* __restrict__ t, float* __restrict__ agg, int e) {
    int tid = blockIdx.x * blockDim.x + threadIdx.x;
    int f = tid & 15;
    int stride = (gridDim.x * blockDim.x) >> 4;
    for (int i = tid >> 4; i < e; i += stride) {
        int s = src[i], d = dst[i];
        atomicAdd(&agg[(size_t)d * 16 + f], t[(size_t)s * 16 + f]);
    }
}

// h[i][f] = relu( dis[i]*(agg[i][f] + t[i][f]) + b[f] )
__global__ void k_finalize64(const float* __restrict__ agg, const float* __restrict__ t,
                             const float* __restrict__ dis, const float* __restrict__ b,
                             float* __restrict__ h, int n) {
    int stride = gridDim.x * blockDim.x;
    for (int idx = blockIdx.x * blockDim.x + threadIdx.x; idx < n * 64; idx += stride) {
        int row = idx >> 6, f = idx & 63;
        float v = dis[row] * (agg[idx] + t[idx]) + b[f];
        h[idx] = v > 0.f ? v : 0.f;
    }
}

// out[i][f] = dis[i]*(agg[i][f] + t[i][f]) + b[f]   (no relu, FOUT=16)
__global__ void k_finalize16(const float* __restrict__ agg, const float* __restrict__ t,
                             const float* __restrict__ dis, const float* __restrict__ b,
                             float* __restrict__ out, int n) {
    int idx = blockIdx.x * blockDim.x + threadIdx.x;
    if (idx < n * 16) {
        int row = idx >> 4, f = idx & 15;
        out[idx] = dis[row] * (agg[idx] + t[idx]) + b[f];
    }
}

extern "C" void kernel_launch(void* const* d_in, const int* in_sizes, int n_in,
                              void* d_out, int out_size, void* d_ws, size_t ws_size,
                              hipStream_t stream) {
    const float* x     = (const float*)d_in[0];
    const int*   ei    = (const int*)d_in[1];
    const float* W_in  = (const float*)d_in[2];
    const float* b_in  = (const float*)d_in[3];
    const float* W_h   = (const float*)d_in[4];
    const float* b_h   = (const float*)d_in[5];
    const float* W_out = (const float*)d_in[6];
    const float* b_out = (const float*)d_in[7];

    const int n = in_sizes[0] / 64;
    const int e = in_sizes[1] / 2;
    const int* src = ei;
    const int* dst = ei + e;

    char* ws = (char*)d_ws;
    size_t off = 0;
    float* dis = (float*)(ws + off); off += (((size_t)n * 4 + 255) & ~(size_t)255);
    float* t   = (float*)(ws + off); off += (size_t)n * 64 * 4;
    float* agg = (float*)(ws + off); off += (size_t)n * 64 * 4;
    float* h   = (float*)(ws + off);

    // degree -> dis = rsqrt(deg)
    k_init_deg<<<(n + 255) / 256, 256, 0, stream>>>(dis, n);
    k_count_deg<<<2048, 256, 0, stream>>>(dst, e, dis);
    k_rsqrt<<<(n + 255) / 256, 256, 0, stream>>>(dis, n);

    // layer 1: x -> h
    k_matmul64<<<4096, 256, 0, stream>>>(x, W_in, dis, t, n);
    hipMemsetAsync(agg, 0, (size_t)n * 64 * 4, stream);
    k_scatter64<<<4096, 256, 0, stream>>>(src, dst, t, agg, e);
    k_finalize64<<<4096, 256, 0, stream>>>(agg, t, dis, b_in, h, n);

    // layers 2,3: h -> h
    for (int l = 0; l < 2; ++l) {
        k_matmul64<<<4096, 256, 0, stream>>>(h, W_h + (size_t)l * 64 * 64, dis, t, n);
        hipMemsetAsync(agg, 0, (size_t)n * 64 * 4, stream);
        k_scatter64<<<4096, 256, 0, stream>>>(src, dst, t, agg, e);
        k_finalize64<<<4096, 256, 0, stream>>>(agg, t, dis, b_h + (size_t)l * 64, h, n);
    }

    // layer 4: h -> out (FOUT=16, no relu)
    k_matmul16<<<4096, 256, 0, stream>>>(h, W_out, dis, t, n);
    hipMemsetAsync(agg, 0, (size_t)n * 16 * 4, stream);
    k_scatter16<<<4096, 256, 0, stream>>>(src, dst, t, agg, e);
    k_finalize16<<<(n * 16 + 255) / 256, 256, 0, stream>>>(agg, t, dis, b_out, (float*)d_out, n);
}

// Round 2
// 700.875 us; speedup vs baseline: 2.1715x; 2.1715x over previous
//
#include <hip/hip_runtime.h>

// GCN: 4 layers (64->64->64->64->16), N=100k nodes, E=1.6M edges (+ self loops).
// out[i] = dis[i] * ( sum_{src->i} t[src] + t[i] ) + b,  t = dis * (h @ W)
// Round 2: CSR-gather instead of atomic scatter (atomics were 400MB/layer of
// L2-writethrough traffic). CSR built per call: hist -> scan -> fill.

// ---------------- degree / norm ----------------

__global__ void k_hist(const int* __restrict__ dst, int e, int* __restrict__ cnt) {
    int i = blockIdx.x * blockDim.x + threadIdx.x;
    if (i < e) atomicAdd(&cnt[dst[i]], 1);
}

__global__ void k_dis(const int* __restrict__ cnt, float* __restrict__ dis, int n) {
    int i = blockIdx.x * blockDim.x + threadIdx.x;
    if (i < n) dis[i] = rsqrtf((float)(cnt[i] + 1));   // +1 self loop
}

// ---------------- exclusive scan (3 kernels) ----------------
// scan1: per-block (1024 elems) exclusive scan + block total
__global__ void k_scan1(const int* __restrict__ cnt, int* __restrict__ excl,
                        int* __restrict__ partials, int n) {
    __shared__ int lds[256];
    int tdx = threadIdx.x;
    int base = blockIdx.x * 1024 + tdx * 4;
    int v[4], s = 0;
#pragma unroll
    for (int k = 0; k < 4; ++k) { int idx = base + k; v[k] = (idx < n) ? cnt[idx] : 0; s += v[k]; }
    lds[tdx] = s;
    __syncthreads();
    for (int off = 1; off < 256; off <<= 1) {
        int x = (tdx >= off) ? lds[tdx - off] : 0;
        __syncthreads();
        if (tdx >= off) lds[tdx] += x;
        __syncthreads();
    }
    int run = lds[tdx] - s;   // exclusive prefix of this thread within block
#pragma unroll
    for (int k = 0; k < 4; ++k) { int idx = base + k; if (idx < n) excl[idx] = run; run += v[k]; }
    if (tdx == 255) partials[blockIdx.x] = lds[255];
}

// scan2: single block, exclusive scan of block totals (handles any nb via loop)
__global__ void k_scan2(int* __restrict__ partials, int nb) {
    __shared__ int lds[128];
    int tdx = threadIdx.x;
    int running = 0;
    for (int base = 0; base < nb; base += 128) {
        int v = (base + tdx < nb) ? partials[base + tdx] : 0;
        lds[tdx] = v;
        __syncthreads();
        for (int off = 1; off < 128; off <<= 1) {
            int x = (tdx >= off) ? lds[tdx - off] : 0;
            __syncthreads();
            if (tdx >= off) lds[tdx] += x;
            __syncthreads();
        }
        int tot = lds[127];
        if (base + tdx < nb) partials[base + tdx] = running + lds[tdx] - v;
        running += tot;
        __syncthreads();
    }
}

// scan3: row_ptr[i] = excl[i] + partials[block]; cursor = copy; row_ptr[n] = e
__global__ void k_scan3(const int* __restrict__ excl, const int* __restrict__ partials,
                        int* __restrict__ row_ptr, int* __restrict__ cursor, int n, int e) {
    int i = blockIdx.x * blockDim.x + threadIdx.x;
    if (i < n) { int v = excl[i] + partials[i >> 10]; row_ptr[i] = v; cursor[i] = v; }
    if (i == 0) row_ptr[n] = e;
}

__global__ void k_fill(const int* __restrict__ src, const int* __restrict__ dst,
                       int* __restrict__ cursor, int* __restrict__ csr_src, int e) {
    int i = blockIdx.x * blockDim.x + threadIdx.x;
    if (i < e) { int p = atomicAdd(&cursor[dst[i]], 1); csr_src[p] = src[i]; }
}

// ---------------- matmul (t = dis * (x @ W)) ----------------

__global__ void k_matmul64(const float* __restrict__ x, const float* __restrict__ W,
                           const float* __restrict__ dis, float* __restrict__ t, int n) {
    __shared__ float Ws[64 * 64];
    for (int i = threadIdx.x; i < 64 * 64; i += blockDim.x) Ws[i] = W[i];
    __syncthreads();
    int lane = threadIdx.x & 63;
    int wid  = (blockIdx.x * blockDim.x + threadIdx.x) >> 6;
    int nw   = (gridDim.x * blockDim.x) >> 6;
    for (int row = wid; row < n; row += nw) {
        float xv  = x[(size_t)row * 64 + lane];
        float acc = 0.f;
#pragma unroll
        for (int k = 0; k < 64; ++k) {
            float xk = __shfl(xv, k);
            acc = fmaf(xk, Ws[k * 64 + lane], acc);
        }
        t[(size_t)row * 64 + lane] = acc * dis[row];
    }
}

__global__ void k_matmul16(const float* __restrict__ x, const float* __restrict__ W,
                           const float* __restrict__ dis, float* __restrict__ t, int n) {
    __shared__ float Ws[64 * 16];
    for (int i = threadIdx.x; i < 64 * 16; i += blockDim.x) Ws[i] = W[i];
    __syncthreads();
    int stride = gridDim.x * blockDim.x;
    for (int idx = blockIdx.x * blockDim.x + threadIdx.x; idx < n * 16; idx += stride) {
        int row = idx >> 4, f = idx & 15;
        const float* xr = x + (size_t)row * 64;
        float acc = 0.f;
#pragma unroll
        for (int k = 0; k < 64; ++k) acc = fmaf(xr[k], Ws[k * 16 + f], acc);
        t[idx] = acc * dis[row];
    }
}

// ---------------- gather (fused aggregate + finalize) ----------------
// one node per 16 lanes; lane holds float4 (4 features). Per edge: 256B coalesced read.
__global__ void k_gather64(const int* __restrict__ row_ptr, const int* __restrict__ csr_src,
                           const float* __restrict__ t, const float* __restrict__ dis,
                           const float* __restrict__ b, float* __restrict__ h, int n) {
    int tid  = blockIdx.x * blockDim.x + threadIdx.x;
    int node = tid >> 4;
    if (node >= n) return;
    int lane15  = threadIdx.x & 15;
    int grpbase = threadIdx.x & 48;          // wave-lane base of this 16-lane group
    int beg = row_ptr[node], end = row_ptr[node + 1];

    float4 acc = *(const float4*)(t + (size_t)node * 64 + lane15 * 4);   // self loop
    for (int j0 = beg; j0 < end; j0 += 16) {
        int myj = j0 + lane15;
        int sv  = (myj < end) ? csr_src[myj] : 0;
        int m   = end - j0; if (m > 16) m = 16;
        for (int k = 0; k < m; ++k) {
            int s = __shfl(sv, grpbase + k);
            const float4 v = *(const float4*)(t + (size_t)s * 64 + lane15 * 4);
            acc.x += v.x; acc.y += v.y; acc.z += v.z; acc.w += v.w;
        }
    }
    float dn = dis[node];
    const float4 bb = *(const float4*)(b + lane15 * 4);
    float4 o;
    o.x = fmaxf(fmaf(dn, acc.x, bb.x), 0.f);
    o.y = fmaxf(fmaf(dn, acc.y, bb.y), 0.f);
    o.z = fmaxf(fmaf(dn, acc.z, bb.z), 0.f);
    o.w = fmaxf(fmaf(dn, acc.w, bb.w), 0.f);
    *(float4*)(h + (size_t)node * 64 + lane15 * 4) = o;
}

// one node per 4 lanes; lane holds float4 (4 of 16 features). No relu.
__global__ void k_gather16(const int* __restrict__ row_ptr, const int* __restrict__ csr_src,
                           const float* __restrict__ t, const float* __restrict__ dis,
                           const float* __restrict__ b, float* __restrict__ out, int n) {
    int tid  = blockIdx.x * blockDim.x + threadIdx.x;
    int node = tid >> 2;
    if (node >= n) return;
    int lane3   = threadIdx.x & 3;
    int grpbase = threadIdx.x & 60;
    int beg = row_ptr[node], end = row_ptr[node + 1];

    float4 acc = *(const float4*)(t + (size_t)node * 16 + lane3 * 4);    // self loop
    for (int j0 = beg; j0 < end; j0 += 4) {
        int myj = j0 + lane3;
        int sv  = (myj < end) ? csr_src[myj] : 0;
        int m   = end - j0; if (m > 4) m = 4;
        for (int k = 0; k < m; ++k) {
            int s = __shfl(sv, grpbase + k);
            const float4 v = *(const float4*)(t + (size_t)s * 16 + lane3 * 4);
            acc.x += v.x; acc.y += v.y; acc.z += v.z; acc.w += v.w;
        }
    }
    float dn = dis[node];
    const float4 bb = *(const float4*)(b + lane3 * 4);
    float4 o;
    o.x = fmaf(dn, acc.x, bb.x);
    o.y = fmaf(dn, acc.y, bb.y);
    o.z = fmaf(dn, acc.z, bb.z);
    o.w = fmaf(dn, acc.w, bb.w);
    *(float4*)(out + (size_t)node * 16 + lane3 * 4) = o;
}

// ---------------- launch ----------------

extern "C" void kernel_launch(void* const* d_in, const int* in_sizes, int n_in,
                              void* d_out, int out_size, void* d_ws, size_t ws_size,
                              hipStream_t stream) {
    const float* x     = (const float*)d_in[0];
    const int*   ei    = (const int*)d_in[1];
    const float* W_in  = (const float*)d_in[2];
    const float* b_in  = (const float*)d_in[3];
    const float* W_h   = (const float*)d_in[4];
    const float* b_h   = (const float*)d_in[5];
    const float* W_out = (const float*)d_in[6];
    const float* b_out = (const float*)d_in[7];

    const int n = in_sizes[0] / 64;
    const int e = in_sizes[1] / 2;
    const int* src = ei;
    const int* dst = ei + e;

    char* ws = (char*)d_ws;
    size_t off = 0;
    auto alloc = [&](size_t bytes) { void* p = ws + off; off += (bytes + 255) & ~(size_t)255; return p; };
    float* dis      = (float*)alloc((size_t)n * 4);
    float* t        = (float*)alloc((size_t)n * 64 * 4);
    float* h        = (float*)alloc((size_t)n * 64 * 4);
    int*   cnt      = (int*)alloc((size_t)n * 4);
    int*   excl     = (int*)alloc((size_t)n * 4);
    int*   row_ptr  = (int*)alloc(((size_t)n + 1) * 4);
    int*   cursor   = (int*)alloc((size_t)n * 4);
    int*   csr_src  = (int*)alloc((size_t)e * 4);
    int*   partials = (int*)alloc(4096);

    const int nb_scan = (n + 1023) / 1024;

    // ---- CSR build ----
    hipMemsetAsync(cnt, 0, (size_t)n * 4, stream);
    k_hist <<<(e + 255) / 256, 256, 0, stream>>>(dst, e, cnt);
    k_dis  <<<(n + 255) / 256, 256, 0, stream>>>(cnt, dis, n);
    k_scan1<<<nb_scan, 256, 0, stream>>>(cnt, excl, partials, n);
    k_scan2<<<1, 128, 0, stream>>>(partials, nb_scan);
    k_scan3<<<(n + 255) / 256, 256, 0, stream>>>(excl, partials, row_ptr, cursor, n, e);
    k_fill <<<(e + 255) / 256, 256, 0, stream>>>(src, dst, cursor, csr_src, e);

    // ---- layer 1: x -> h ----
    k_matmul64<<<4096, 256, 0, stream>>>(x, W_in, dis, t, n);
    k_gather64<<<(n * 16 + 255) / 256, 256, 0, stream>>>(row_ptr, csr_src, t, dis, b_in, h, n);

    // ---- layers 2,3: h -> h ----
    for (int l = 0; l < 2; ++l) {
        k_matmul64<<<4096, 256, 0, stream>>>(h, W_h + (size_t)l * 64 * 64, dis, t, n);
        k_gather64<<<(n * 16 + 255) / 256, 256, 0, stream>>>(row_ptr, csr_src, t, dis,
                                                             b_h + (size_t)l * 64, h, n);
    }

    // ---- layer 4: h -> out (FOUT=16, no relu) ----
    k_matmul16<<<4096, 256, 0, stream>>>(h, W_out, dis, t, n);
    k_gather16<<<(n * 4 + 255) / 256, 256, 0, stream>>>(row_ptr, csr_src, t, dis, b_out,
                                                        (float*)d_out, n);
}